// Round 3
// baseline (795.544 us; speedup 1.0000x reference)
//
#include <hip/hip_runtime.h>

// ---------------------------------------------------------------------------
// GCN forward: h0=[time,type] -> GraphConv(relu) -> GraphConv(relu)
//              -> per-graph mean pool -> linear [G,2]
//
// Strategy:
//  * degrees via int atomics; scales = 1/sqrt(max(deg,1))
//  * layer-1 aggregate v = D_in^-1/2 A D_out^-1/2 h0  is only [N,2] (atomics)
//  * CSR-by-dst (histogram + 3-kernel device-wide scan + bucket fill)
//  * layer-2 aggregation: WAVE per node; per edge RECOMPUTE
//    h1[src] = relu(v_src @ W1 + b1) in registers (v_src is 2 floats) —
//    no [N,256] gather, no atomics. Lane owns 4 channels. Writes agg2 [N,256].
//  * fused GEMM: h2 = relu(agg2 @ W2 + b2); p = h2 @ Wc; shuffle-reduce and
//    atomicAdd p into per-graph pool. out = pool/cnt + bc.
//    A-tile stored k-major in LDS so the inner loop is 3x ds_read_b128.
// ---------------------------------------------------------------------------

#define HDIM 256

__global__ __launch_bounds__(256) void deg_kernel(
    const int* __restrict__ src, const int* __restrict__ dst,
    int* __restrict__ deg_out, int* __restrict__ deg_in, int E)
{
    int e = blockIdx.x * 256 + threadIdx.x;
    if (e < E) {
        atomicAdd(&deg_out[src[e]], 1);
        atomicAdd(&deg_in[dst[e]], 1);
    }
}

__global__ __launch_bounds__(256) void node_kernel(
    const int* __restrict__ deg_out, const int* __restrict__ deg_in,
    const int* __restrict__ gid, float* __restrict__ os, float* __restrict__ isc,
    int* __restrict__ gcnt, int N)
{
    int i = blockIdx.x * 256 + threadIdx.x;
    if (i < N) {
        os[i]  = 1.0f / sqrtf(fmaxf((float)deg_out[i], 1.0f));
        isc[i] = 1.0f / sqrtf(fmaxf((float)deg_in[i], 1.0f));
        atomicAdd(&gcnt[gid[i]], 1);
    }
}

__global__ __launch_bounds__(256) void scatter_v_kernel(
    const int* __restrict__ src, const int* __restrict__ dst,
    const float* __restrict__ t, const float* __restrict__ u,
    const float* __restrict__ os, float* __restrict__ v, int E)
{
    int e = blockIdx.x * 256 + threadIdx.x;
    if (e < E) {
        int s = src[e], d = dst[e];
        float sc = os[s];
        atomicAdd(&v[2 * d + 0], sc * t[s]);
        atomicAdd(&v[2 * d + 1], sc * u[s]);
    }
}

// ---- device-wide exclusive scan of deg_in (3 kernels, N <= 64*1024) --------
__global__ __launch_bounds__(1024) void scan_local_kernel(
    const int* __restrict__ deg, int* __restrict__ loc,
    int* __restrict__ partials, int N)
{
    __shared__ int lds[1024];
    int tid = threadIdx.x;
    int idx = blockIdx.x * 1024 + tid;
    int x = (idx < N) ? deg[idx] : 0;
    int val = x;
    lds[tid] = val;
    __syncthreads();
    for (int d = 1; d < 1024; d <<= 1) {
        int tv = (tid >= d) ? lds[tid - d] : 0;
        __syncthreads();
        val += tv;
        lds[tid] = val;
        __syncthreads();
    }
    if (idx < N) loc[idx] = val - x;              // exclusive within block
    if (tid == 1023) partials[blockIdx.x] = val;  // block total
}

__global__ __launch_bounds__(64) void scan_partials_kernel(
    int* __restrict__ partials, int nb)
{
    int lane = threadIdx.x;
    int x = (lane < nb) ? partials[lane] : 0;
    int v = x;
    #pragma unroll
    for (int d = 1; d < 64; d <<= 1) {
        int tv = __shfl_up(v, d);
        if (lane >= d) v += tv;
    }
    if (lane < nb) partials[lane] = v - x;        // exclusive
}

__global__ __launch_bounds__(256) void scan_add_kernel(
    const int* __restrict__ loc, const int* __restrict__ partials,
    int* __restrict__ offs, int* __restrict__ cursor, int N, int E)
{
    int i = blockIdx.x * 256 + threadIdx.x;
    if (i < N) {
        int vv = loc[i] + partials[i >> 10];
        offs[i] = vv;
        cursor[i] = vv;
    }
    if (i == 0) offs[N] = E;
}
// ---------------------------------------------------------------------------

__global__ __launch_bounds__(256) void fill_csr_kernel(
    const int* __restrict__ src, const int* __restrict__ dst,
    int* __restrict__ cursor, int* __restrict__ csr, int E)
{
    int e = blockIdx.x * 256 + threadIdx.x;
    if (e < E) {
        int pos = atomicAdd(&cursor[dst[e]], 1);
        csr[pos] = src[e];
    }
}

__global__ __launch_bounds__(256) void pack_kernel(
    const float* __restrict__ v, const float* __restrict__ os,
    const float* __restrict__ isc, float4* __restrict__ pack, int N)
{
    int i = blockIdx.x * 256 + threadIdx.x;
    if (i < N) {
        float s = isc[i];
        pack[i] = make_float4(v[2 * i] * s, v[2 * i + 1] * s, os[i], 0.0f);
    }
}

// one WAVE per node; lane owns channels lane + 64q (q=0..3).
// agg2[i][j] = isc[i] * sum_{src in N_in(i)} os[src]*relu(v_src@W1[:,j]+b1[j])
__global__ __launch_bounds__(256) void agg_kernel(
    const int* __restrict__ offs, const int* __restrict__ csr,
    const float4* __restrict__ pack, const float* __restrict__ isc,
    const float* __restrict__ W1, const float* __restrict__ b1,
    float* __restrict__ agg2, int N)
{
    int wave = threadIdx.x >> 6;
    int lane = threadIdx.x & 63;
    int i = blockIdx.x * 4 + wave;
    if (i >= N) return;

    float w0[4], w1[4], bb[4], acc[4] = {0.f, 0.f, 0.f, 0.f};
    #pragma unroll
    for (int q = 0; q < 4; ++q) {
        int j = lane + 64 * q;
        w0[q] = W1[j];
        w1[q] = W1[HDIM + j];
        bb[q] = b1[j];
    }

    int e0 = offs[i], e1 = offs[i + 1];
    for (int e = e0; e < e1; ++e) {
        int s = csr[e];                  // wave-uniform broadcast load
        float4 pk = pack[s];             // broadcast
        #pragma unroll
        for (int q = 0; q < 4; ++q) {
            float h = fmaxf(fmaf(pk.x, w0[q], fmaf(pk.y, w1[q], bb[q])), 0.0f);
            acc[q] = fmaf(pk.z, h, acc[q]);
        }
    }
    float s2 = isc[i];
    #pragma unroll
    for (int q = 0; q < 4; ++q)
        agg2[(size_t)i * HDIM + lane + 64 * q] = acc[q] * s2;
}

// fused: h2 = relu(agg2 @ W2 + b2); p = h2 @ Wc; pool[g] += p (reduced)
// block = 256 threads, BM=32 rows, BN=256 (all cols), BK=32.
// A tile stored K-MAJOR (As_t[k][row]) so per-k A read is one broadcast b128.
// thread (tr=tid/32, tc=tid%32): rows tr*4+{0..3}, cols tc*4+{0..3} and 128+tc*4+{0..3}
__global__ __launch_bounds__(256) void gemm_pool_kernel(
    const float* __restrict__ agg2, const float* __restrict__ W2,
    const float* __restrict__ b2, const float* __restrict__ Wc,
    const int* __restrict__ gid, float* __restrict__ pool, int N)
{
    __shared__ float As_t[32][33];   // [k][row], +1 pad
    __shared__ float Bs[32][HDIM];   // 32 KB
    int tid = threadIdx.x;
    int m0 = blockIdx.x * 32;
    int tr = tid >> 5;
    int tc = tid & 31;

    float accL[4][4] = {};
    float accH[4][4] = {};

    for (int k0 = 0; k0 < HDIM; k0 += 32) {
        // stage A tile (32 rows x 32 k) transposed into k-major, guarded
        int r = tid >> 3, kq = tid & 7;
        float4 av = make_float4(0.f, 0.f, 0.f, 0.f);
        if (m0 + r < N)
            av = *(const float4*)&agg2[(size_t)(m0 + r) * HDIM + k0 + kq * 4];
        As_t[kq * 4 + 0][r] = av.x;
        As_t[kq * 4 + 1][r] = av.y;
        As_t[kq * 4 + 2][r] = av.z;
        As_t[kq * 4 + 3][r] = av.w;
        // stage B tile (32 k x 256 cols)
        #pragma unroll
        for (int it = 0; it < 8; ++it) {
            int L = tid + it * 256;       // 0..2047 float4s
            int row = L >> 6;
            int c4 = L & 63;
            *(float4*)&Bs[row][c4 * 4] =
                *(const float4*)&W2[(size_t)(k0 + row) * HDIM + c4 * 4];
        }
        __syncthreads();

        #pragma unroll 8
        for (int k = 0; k < 32; ++k) {
            float4 a  = *(const float4*)&As_t[k][tr * 4];      // broadcast b128
            float4 bl = *(const float4*)&Bs[k][tc * 4];
            float4 bh = *(const float4*)&Bs[k][128 + tc * 4];
            accL[0][0] = fmaf(a.x, bl.x, accL[0][0]); accL[0][1] = fmaf(a.x, bl.y, accL[0][1]);
            accL[0][2] = fmaf(a.x, bl.z, accL[0][2]); accL[0][3] = fmaf(a.x, bl.w, accL[0][3]);
            accL[1][0] = fmaf(a.y, bl.x, accL[1][0]); accL[1][1] = fmaf(a.y, bl.y, accL[1][1]);
            accL[1][2] = fmaf(a.y, bl.z, accL[1][2]); accL[1][3] = fmaf(a.y, bl.w, accL[1][3]);
            accL[2][0] = fmaf(a.z, bl.x, accL[2][0]); accL[2][1] = fmaf(a.z, bl.y, accL[2][1]);
            accL[2][2] = fmaf(a.z, bl.z, accL[2][2]); accL[2][3] = fmaf(a.z, bl.w, accL[2][3]);
            accL[3][0] = fmaf(a.w, bl.x, accL[3][0]); accL[3][1] = fmaf(a.w, bl.y, accL[3][1]);
            accL[3][2] = fmaf(a.w, bl.z, accL[3][2]); accL[3][3] = fmaf(a.w, bl.w, accL[3][3]);
            accH[0][0] = fmaf(a.x, bh.x, accH[0][0]); accH[0][1] = fmaf(a.x, bh.y, accH[0][1]);
            accH[0][2] = fmaf(a.x, bh.z, accH[0][2]); accH[0][3] = fmaf(a.x, bh.w, accH[0][3]);
            accH[1][0] = fmaf(a.y, bh.x, accH[1][0]); accH[1][1] = fmaf(a.y, bh.y, accH[1][1]);
            accH[1][2] = fmaf(a.y, bh.z, accH[1][2]); accH[1][3] = fmaf(a.y, bh.w, accH[1][3]);
            accH[2][0] = fmaf(a.z, bh.x, accH[2][0]); accH[2][1] = fmaf(a.z, bh.y, accH[2][1]);
            accH[2][2] = fmaf(a.z, bh.z, accH[2][2]); accH[2][3] = fmaf(a.z, bh.w, accH[2][3]);
            accH[3][0] = fmaf(a.w, bh.x, accH[3][0]); accH[3][1] = fmaf(a.w, bh.y, accH[3][1]);
            accH[3][2] = fmaf(a.w, bh.z, accH[3][2]); accH[3][3] = fmaf(a.w, bh.w, accH[3][3]);
        }
        __syncthreads();
    }

    // epilogue: bias + relu + project with Wc, reduce over 32 lanes, atomic pool
    float pc[4][2] = {};
    #pragma unroll
    for (int j = 0; j < 4; ++j) {
        int colL = tc * 4 + j;
        int colH = 128 + tc * 4 + j;
        float bL = b2[colL], bH = b2[colH];
        float wL0 = Wc[colL * 2 + 0], wL1 = Wc[colL * 2 + 1];
        float wH0 = Wc[colH * 2 + 0], wH1 = Wc[colH * 2 + 1];
        #pragma unroll
        for (int i = 0; i < 4; ++i) {
            float hL = fmaxf(accL[i][j] + bL, 0.0f);
            float hH = fmaxf(accH[i][j] + bH, 0.0f);
            pc[i][0] = fmaf(hL, wL0, fmaf(hH, wH0, pc[i][0]));
            pc[i][1] = fmaf(hL, wL1, fmaf(hH, wH1, pc[i][1]));
        }
    }
    // reduce across the 32 lanes sharing this row group (xor masks <32 stay in-half)
    #pragma unroll
    for (int off = 16; off > 0; off >>= 1) {
        #pragma unroll
        for (int i = 0; i < 4; ++i) {
            pc[i][0] += __shfl_xor(pc[i][0], off);
            pc[i][1] += __shfl_xor(pc[i][1], off);
        }
    }
    if (tc == 0) {
        #pragma unroll
        for (int i = 0; i < 4; ++i) {
            int rr = m0 + tr * 4 + i;
            if (rr < N) {
                int g = gid[rr];
                atomicAdd(&pool[g * 2 + 0], pc[i][0]);
                atomicAdd(&pool[g * 2 + 1], pc[i][1]);
            }
        }
    }
}

__global__ __launch_bounds__(256) void finalize_kernel(
    const float* __restrict__ pool, const int* __restrict__ gcnt,
    const float* __restrict__ bc, float* __restrict__ out, int G)
{
    int g = threadIdx.x;
    if (g < G) {
        float c = fmaxf((float)gcnt[g], 1.0f);
        out[2 * g + 0] = pool[2 * g + 0] / c + bc[0];
        out[2 * g + 1] = pool[2 * g + 1] / c + bc[1];
    }
}

extern "C" void kernel_launch(void* const* d_in, const int* in_sizes, int n_in,
                              void* d_out, int out_size, void* d_ws, size_t ws_size,
                              hipStream_t stream)
{
    const float* t  = (const float*)d_in[0];
    const float* u  = (const float*)d_in[1];
    const int* esrc = (const int*)d_in[2];
    const int* edst = (const int*)d_in[3];
    const int* gid  = (const int*)d_in[4];
    const float* W1 = (const float*)d_in[6];
    const float* b1 = (const float*)d_in[7];
    const float* W2 = (const float*)d_in[8];
    const float* b2 = (const float*)d_in[9];
    const float* Wc = (const float*)d_in[10];
    const float* bc = (const float*)d_in[11];
    float* out = (float*)d_out;

    int N = in_sizes[0];
    int E = in_sizes[2];
    int G = out_size / 2;

    char* ws = (char*)d_ws;
    size_t off = 0;
    auto take = [&](size_t bytes) {
        size_t o = off;
        off += (bytes + 15) & ~(size_t)15;
        return o;
    };
    int*    deg_out = (int*)   (ws + take(4 * (size_t)N));
    int*    deg_in  = (int*)   (ws + take(4 * (size_t)N));
    float*  v       = (float*) (ws + take(8 * (size_t)N));
    float*  pool    = (float*) (ws + take(8 * (size_t)G));
    int*    gcnt    = (int*)   (ws + take(4 * (size_t)G));
    size_t  zbytes  = off;                               // zero everything above
    float*  os      = (float*) (ws + take(4 * (size_t)N));
    float*  isc     = (float*) (ws + take(4 * (size_t)N));
    int*    offs    = (int*)   (ws + take(4 * (size_t)(N + 1)));
    int*    cursor  = (int*)   (ws + take(4 * (size_t)N));
    int*    loc     = (int*)   (ws + take(4 * (size_t)N));
    int*    partials= (int*)   (ws + take(4 * 64));
    int*    csr     = (int*)   (ws + take(4 * (size_t)E));
    float4* pack    = (float4*)(ws + take(16 * (size_t)N));
    float*  agg2    = (float*) (ws + take((size_t)N * HDIM * 4));

    hipMemsetAsync(ws, 0, zbytes, stream);

    int eb = (E + 255) / 256;
    int nb = (N + 255) / 256;
    int sb = (N + 1023) / 1024;     // scan blocks (<=64 for N<=65536)
    deg_kernel          <<<eb, 256, 0, stream>>>(esrc, edst, deg_out, deg_in, E);
    node_kernel         <<<nb, 256, 0, stream>>>(deg_out, deg_in, gid, os, isc, gcnt, N);
    scatter_v_kernel    <<<eb, 256, 0, stream>>>(esrc, edst, t, u, os, v, E);
    scan_local_kernel   <<<sb, 1024, 0, stream>>>(deg_in, loc, partials, N);
    scan_partials_kernel<<<1, 64, 0, stream>>>(partials, sb);
    scan_add_kernel     <<<nb, 256, 0, stream>>>(loc, partials, offs, cursor, N, E);
    fill_csr_kernel     <<<eb, 256, 0, stream>>>(esrc, edst, cursor, csr, E);
    pack_kernel         <<<nb, 256, 0, stream>>>(v, os, isc, pack, N);
    agg_kernel          <<<(N + 3) / 4, 256, 0, stream>>>(offs, csr, pack, isc, W1, b1, agg2, N);
    gemm_pool_kernel    <<<(N + 31) / 32, 256, 0, stream>>>(agg2, W2, b2, Wc, gid, pool, N);
    finalize_kernel     <<<1, 256, 0, stream>>>(pool, gcnt, bc, out, G);
}

// Round 4
// 649.516 us; speedup vs baseline: 1.2248x; 1.2248x over previous
//
#include <hip/hip_runtime.h>

// ---------------------------------------------------------------------------
// GCN forward: h0=[time,type] -> GraphConv(relu) -> GraphConv(relu)
//              -> per-graph mean pool -> linear [G,2]
//
//  * degrees via int atomics; scales = 1/sqrt(max(deg,1))
//  * CSR-by-dst (histogram + 3-kernel device-wide scan + bucket fill)
//  * vpack: CSR-based layer-1 aggregate (16-lane group/node, shfl reduce,
//    NO atomics) fused with pack = {v0*isc, v1*isc, os}
//  * agg: WAVE per node; per edge RECOMPUTE h1[src]=relu(v_src@W1+b1) in regs
//  * gemm_pool: h2 = relu(agg2@W2+b2); p = h2@Wc; pool[g] += p.
//    BM=64 BN=256 BK=16, 8x8/thread, double-buffered LDS (40960B = 4 blk/CU),
//    B staged via global_load_lds(16B), A reg-staged + transposed ds_write.
//    Stage(t+1) issued BEFORE compute(t) so latency hides under FMAs.
// ---------------------------------------------------------------------------

#define HDIM 256

__global__ __launch_bounds__(256) void deg_kernel(
    const int* __restrict__ src, const int* __restrict__ dst,
    int* __restrict__ deg_out, int* __restrict__ deg_in, int E)
{
    int e = blockIdx.x * 256 + threadIdx.x;
    if (e < E) {
        atomicAdd(&deg_out[src[e]], 1);
        atomicAdd(&deg_in[dst[e]], 1);
    }
}

__global__ __launch_bounds__(256) void node_kernel(
    const int* __restrict__ deg_out, const int* __restrict__ deg_in,
    const int* __restrict__ gid, float* __restrict__ os, float* __restrict__ isc,
    int* __restrict__ gcnt, int N)
{
    int i = blockIdx.x * 256 + threadIdx.x;
    if (i < N) {
        os[i]  = 1.0f / sqrtf(fmaxf((float)deg_out[i], 1.0f));
        isc[i] = 1.0f / sqrtf(fmaxf((float)deg_in[i], 1.0f));
        atomicAdd(&gcnt[gid[i]], 1);
    }
}

// ---- device-wide exclusive scan of deg_in (3 kernels, N <= 64*1024) --------
__global__ __launch_bounds__(1024) void scan_local_kernel(
    const int* __restrict__ deg, int* __restrict__ loc,
    int* __restrict__ partials, int N)
{
    __shared__ int lds[1024];
    int tid = threadIdx.x;
    int idx = blockIdx.x * 1024 + tid;
    int x = (idx < N) ? deg[idx] : 0;
    int val = x;
    lds[tid] = val;
    __syncthreads();
    for (int d = 1; d < 1024; d <<= 1) {
        int tv = (tid >= d) ? lds[tid - d] : 0;
        __syncthreads();
        val += tv;
        lds[tid] = val;
        __syncthreads();
    }
    if (idx < N) loc[idx] = val - x;              // exclusive within block
    if (tid == 1023) partials[blockIdx.x] = val;  // block total
}

__global__ __launch_bounds__(64) void scan_partials_kernel(
    int* __restrict__ partials, int nb)
{
    int lane = threadIdx.x;
    int x = (lane < nb) ? partials[lane] : 0;
    int v = x;
    #pragma unroll
    for (int d = 1; d < 64; d <<= 1) {
        int tv = __shfl_up(v, d);
        if (lane >= d) v += tv;
    }
    if (lane < nb) partials[lane] = v - x;        // exclusive
}

__global__ __launch_bounds__(256) void scan_add_kernel(
    const int* __restrict__ loc, const int* __restrict__ partials,
    int* __restrict__ offs, int* __restrict__ cursor, int N, int E)
{
    int i = blockIdx.x * 256 + threadIdx.x;
    if (i < N) {
        int vv = loc[i] + partials[i >> 10];
        offs[i] = vv;
        cursor[i] = vv;
    }
    if (i == 0) offs[N] = E;
}
// ---------------------------------------------------------------------------

__global__ __launch_bounds__(256) void fill_csr_kernel(
    const int* __restrict__ src, const int* __restrict__ dst,
    int* __restrict__ cursor, int* __restrict__ csr, int E)
{
    int e = blockIdx.x * 256 + threadIdx.x;
    if (e < E) {
        int pos = atomicAdd(&cursor[dst[e]], 1);
        csr[pos] = src[e];
    }
}

// layer-1 aggregate via CSR (no atomics) fused with pack build.
// 16-lane group per node: pack[i] = {v0*isc, v1*isc, os, 0}
__global__ __launch_bounds__(256) void vpack_kernel(
    const int* __restrict__ offs, const int* __restrict__ csr,
    const float* __restrict__ t, const float* __restrict__ u,
    const float* __restrict__ os, const float* __restrict__ isc,
    float4* __restrict__ pack, int N)
{
    int grp = threadIdx.x >> 4;
    int l   = threadIdx.x & 15;
    int i = blockIdx.x * 16 + grp;
    if (i >= N) return;
    int e0 = offs[i], e1 = offs[i + 1];
    float a0 = 0.0f, a1 = 0.0f;
    for (int e = e0 + l; e < e1; e += 16) {
        int s = csr[e];
        float sc = os[s];
        a0 = fmaf(sc, t[s], a0);
        a1 = fmaf(sc, u[s], a1);
    }
    #pragma unroll
    for (int d = 8; d; d >>= 1) {
        a0 += __shfl_xor(a0, d);
        a1 += __shfl_xor(a1, d);
    }
    if (l == 0) {
        float s2 = isc[i];
        pack[i] = make_float4(a0 * s2, a1 * s2, os[i], 0.0f);
    }
}

// one WAVE per node; lane owns channels lane + 64q (q=0..3).
__global__ __launch_bounds__(256) void agg_kernel(
    const int* __restrict__ offs, const int* __restrict__ csr,
    const float4* __restrict__ pack, const float* __restrict__ isc,
    const float* __restrict__ W1, const float* __restrict__ b1,
    float* __restrict__ agg2, int N)
{
    int wave = threadIdx.x >> 6;
    int lane = threadIdx.x & 63;
    int i = blockIdx.x * 4 + wave;
    if (i >= N) return;

    float w0[4], w1[4], bb[4], acc[4] = {0.f, 0.f, 0.f, 0.f};
    #pragma unroll
    for (int q = 0; q < 4; ++q) {
        int j = lane + 64 * q;
        w0[q] = W1[j];
        w1[q] = W1[HDIM + j];
        bb[q] = b1[j];
    }

    int e0 = offs[i], e1 = offs[i + 1];
    for (int e = e0; e < e1; ++e) {
        int s = csr[e];
        float4 pk = pack[s];
        #pragma unroll
        for (int q = 0; q < 4; ++q) {
            float h = fmaxf(fmaf(pk.x, w0[q], fmaf(pk.y, w1[q], bb[q])), 0.0f);
            acc[q] = fmaf(pk.z, h, acc[q]);
        }
    }
    float s2 = isc[i];
    #pragma unroll
    for (int q = 0; q < 4; ++q)
        agg2[(size_t)i * HDIM + lane + 64 * q] = acc[q] * s2;
}

// fused GEMM + pool. BM=64 BN=256 BK=16; 256 thr; thread = 8 rows x 8 cols.
// tr=tid>>5 (8 row-groups of 8), tc=tid&31 (cols tc*8..+8).
__global__ __launch_bounds__(256, 4) void gemm_pool_kernel(
    const float* __restrict__ agg2, const float* __restrict__ W2,
    const float* __restrict__ b2, const float* __restrict__ Wc,
    const int* __restrict__ gid, float* __restrict__ pool, int N)
{
    __shared__ float Ab[2][16][64];    // k-major A tiles (dbuf)  8 KB
    __shared__ float Bb[2][16][256];   // row-major B tiles (dbuf) 32 KB
    int tid  = threadIdx.x;
    int m0   = blockIdx.x * 64;
    int tr   = tid >> 5;
    int tc   = tid & 31;
    int w    = tid >> 6;
    int lane = tid & 63;
    int r    = tid >> 2;           // staging row 0..63
    int kq4  = (tid & 3) * 4;      // staging k sub-offset

    float acc[8][8] = {};

    // ---- staging helpers -------------------------------------------------
    auto stage_issue = [&](int t1, int b1, float4& aA) {
        int k0 = t1 * 16;
        // B tile: 16 rows x 1 KB, wave w covers rows w*4..w*4+3 (HW adds lane*16)
        #pragma unroll
        for (int j = 0; j < 4; ++j) {
            int rw = w * 4 + j;
            const float* gsrc = W2 + (size_t)(k0 + rw) * HDIM + lane * 4;
            __builtin_amdgcn_global_load_lds(
                (const __attribute__((address_space(1))) unsigned int*)gsrc,
                (__attribute__((address_space(3))) unsigned int*)&Bb[b1][rw][0],
                16, 0, 0);
        }
        // A tile: issue the global load now; LDS write deferred (issue-early)
        int row = m0 + r;
        if (row > N - 1) row = N - 1;          // clamp: result rows >=N discarded
        aA = *(const float4*)&agg2[(size_t)row * HDIM + k0 + kq4];
    };
    auto stage_write = [&](int b1, const float4& aA) {
        Ab[b1][kq4 + 0][r] = aA.x;
        Ab[b1][kq4 + 1][r] = aA.y;
        Ab[b1][kq4 + 2][r] = aA.z;
        Ab[b1][kq4 + 3][r] = aA.w;
    };

    // ---- prologue --------------------------------------------------------
    {
        float4 a0;
        stage_issue(0, 0, a0);
        stage_write(0, a0);
    }
    __syncthreads();

    // ---- main loop: stage(t+1) || compute(t) -----------------------------
    for (int t = 0; t < 16; ++t) {
        int b = t & 1;
        float4 aN;
        if (t < 15) stage_issue(t + 1, b ^ 1, aN);

        const float* Ak = &Ab[b][0][0];
        const float* Bk = &Bb[b][0][0];
        #pragma unroll 2
        for (int kk = 0; kk < 16; ++kk) {
            float4 a0 = *(const float4*)(Ak + kk * 64 + tr * 8);
            float4 a1 = *(const float4*)(Ak + kk * 64 + tr * 8 + 4);
            float4 b0 = *(const float4*)(Bk + kk * 256 + tc * 8);
            float4 b1 = *(const float4*)(Bk + kk * 256 + tc * 8 + 4);
            float av[8] = {a0.x, a0.y, a0.z, a0.w, a1.x, a1.y, a1.z, a1.w};
            float bv[8] = {b0.x, b0.y, b0.z, b0.w, b1.x, b1.y, b1.z, b1.w};
            #pragma unroll
            for (int i = 0; i < 8; ++i)
                #pragma unroll
                for (int j = 0; j < 8; ++j)
                    acc[i][j] = fmaf(av[i], bv[j], acc[i][j]);
        }

        if (t < 15) stage_write(b ^ 1, aN);
        __syncthreads();
    }

    // ---- epilogue: bias+relu, project to 2, half-wave reduce, atomic pool -
    float pc[8][2] = {};
    #pragma unroll
    for (int j = 0; j < 8; ++j) {
        int col = tc * 8 + j;
        float bcol = b2[col];
        float wc0 = Wc[col * 2 + 0], wc1 = Wc[col * 2 + 1];
        #pragma unroll
        for (int i = 0; i < 8; ++i) {
            float h = fmaxf(acc[i][j] + bcol, 0.0f);
            pc[i][0] = fmaf(h, wc0, pc[i][0]);
            pc[i][1] = fmaf(h, wc1, pc[i][1]);
        }
    }
    #pragma unroll
    for (int off = 16; off > 0; off >>= 1) {
        #pragma unroll
        for (int i = 0; i < 8; ++i) {
            pc[i][0] += __shfl_xor(pc[i][0], off);
            pc[i][1] += __shfl_xor(pc[i][1], off);
        }
    }
    if (tc == 0) {
        #pragma unroll
        for (int i = 0; i < 8; ++i) {
            int rr = m0 + tr * 8 + i;
            if (rr < N) {
                int g = gid[rr];
                atomicAdd(&pool[g * 2 + 0], pc[i][0]);
                atomicAdd(&pool[g * 2 + 1], pc[i][1]);
            }
        }
    }
}

__global__ __launch_bounds__(256) void finalize_kernel(
    const float* __restrict__ pool, const int* __restrict__ gcnt,
    const float* __restrict__ bc, float* __restrict__ out, int G)
{
    int g = threadIdx.x;
    if (g < G) {
        float c = fmaxf((float)gcnt[g], 1.0f);
        out[2 * g + 0] = pool[2 * g + 0] / c + bc[0];
        out[2 * g + 1] = pool[2 * g + 1] / c + bc[1];
    }
}

extern "C" void kernel_launch(void* const* d_in, const int* in_sizes, int n_in,
                              void* d_out, int out_size, void* d_ws, size_t ws_size,
                              hipStream_t stream)
{
    const float* t  = (const float*)d_in[0];
    const float* u  = (const float*)d_in[1];
    const int* esrc = (const int*)d_in[2];
    const int* edst = (const int*)d_in[3];
    const int* gid  = (const int*)d_in[4];
    const float* W1 = (const float*)d_in[6];
    const float* b1 = (const float*)d_in[7];
    const float* W2 = (const float*)d_in[8];
    const float* b2 = (const float*)d_in[9];
    const float* Wc = (const float*)d_in[10];
    const float* bc = (const float*)d_in[11];
    float* out = (float*)d_out;

    int N = in_sizes[0];
    int E = in_sizes[2];
    int G = out_size / 2;

    char* ws = (char*)d_ws;
    size_t off = 0;
    auto take = [&](size_t bytes) {
        size_t o = off;
        off += (bytes + 15) & ~(size_t)15;
        return o;
    };
    int*    deg_out = (int*)   (ws + take(4 * (size_t)N));
    int*    deg_in  = (int*)   (ws + take(4 * (size_t)N));
    float*  pool    = (float*) (ws + take(8 * (size_t)G));
    int*    gcnt    = (int*)   (ws + take(4 * (size_t)G));
    size_t  zbytes  = off;                               // zero everything above
    float*  os      = (float*) (ws + take(4 * (size_t)N));
    float*  isc     = (float*) (ws + take(4 * (size_t)N));
    int*    offs    = (int*)   (ws + take(4 * (size_t)(N + 1)));
    int*    cursor  = (int*)   (ws + take(4 * (size_t)N));
    int*    loc     = (int*)   (ws + take(4 * (size_t)N));
    int*    partials= (int*)   (ws + take(4 * 64));
    int*    csr     = (int*)   (ws + take(4 * (size_t)E));
    float4* pack    = (float4*)(ws + take(16 * (size_t)N));
    float*  agg2    = (float*) (ws + take((size_t)N * HDIM * 4));

    hipMemsetAsync(ws, 0, zbytes, stream);

    int eb = (E + 255) / 256;
    int nb = (N + 255) / 256;
    int sb = (N + 1023) / 1024;     // scan blocks (<=64 for N<=65536)
    deg_kernel          <<<eb, 256, 0, stream>>>(esrc, edst, deg_out, deg_in, E);
    node_kernel         <<<nb, 256, 0, stream>>>(deg_out, deg_in, gid, os, isc, gcnt, N);
    scan_local_kernel   <<<sb, 1024, 0, stream>>>(deg_in, loc, partials, N);
    scan_partials_kernel<<<1, 64, 0, stream>>>(partials, sb);
    scan_add_kernel     <<<nb, 256, 0, stream>>>(loc, partials, offs, cursor, N, E);
    fill_csr_kernel     <<<eb, 256, 0, stream>>>(esrc, edst, cursor, csr, E);
    vpack_kernel        <<<(N + 15) / 16, 256, 0, stream>>>(offs, csr, t, u, os, isc, pack, N);
    agg_kernel          <<<(N + 3) / 4, 256, 0, stream>>>(offs, csr, pack, isc, W1, b1, agg2, N);
    gemm_pool_kernel    <<<(N + 63) / 64, 256, 0, stream>>>(agg2, W2, b2, Wc, gid, pool, N);
    finalize_kernel     <<<1, 256, 0, stream>>>(pool, gcnt, bc, out, G);
}